// Round 1
// baseline (230.794 us; speedup 1.0000x reference)
//
#include <hip/hip_runtime.h>
#include <math.h>

#define DIM 64
#define SCAN_BLOCK 1024
#define NB1 1024          // coarse bins (dst>>7 <= 781 for n=100000)
#define NBLK2 256         // blocks in coarse count/scatter phases
#define TPB2 1024         // threads per block in coarse phases
#define LEN2 (NB1 * NBLK2)
#define BUCKET_BITS 7
#define BUCKET_SZ 128     // nodes per coarse bucket
#define SRC_SHIFT 20      // src fits in 17 bits; dst low-7 packed above

__device__ __forceinline__ float lrelu(float x) { return x > 0.f ? x : 0.01f * x; }
__device__ __forceinline__ float elu(float x)  { return x > 0.f ? x : expm1f(x); }

// ---------------------------------------------------------------------------
// Fused Kernel A: blocks [0, NBLK2) do the coarse dst histogram; the rest do
// per-node scores + bf16 feature copy. The two are independent -> overlap.
// ---------------------------------------------------------------------------
__global__ void prep_and_count(const float* __restrict__ feat,
                               const float* __restrict__ attn_w,
                               float* __restrict__ s_src,
                               float* __restrict__ s_dst,
                               unsigned short* __restrict__ fbf,
                               int n_nodes,
                               const int* __restrict__ dst,
                               int* __restrict__ bcntT, int m) {
    __shared__ int lhist[NB1];
    if (blockIdx.x < NBLK2) {
        // ---- coarse count (block-major store, coalesced) ----
        int cb = blockIdx.x;
        for (int t = threadIdx.x; t < NB1; t += blockDim.x) lhist[t] = 0;
        __syncthreads();
        int chunk = (m + NBLK2 - 1) / NBLK2;
        int lo = cb * chunk;
        int hi = min(m, lo + chunk);
        for (int i = lo + threadIdx.x; i < hi; i += blockDim.x)
            atomicAdd(&lhist[dst[i] >> BUCKET_BITS], 1);         // LDS atomic
        __syncthreads();
        for (int t = threadIdx.x; t < NB1; t += blockDim.x)
            bcntT[(size_t)cb * NB1 + t] = lhist[t];
        return;
    }
    // ---- prep: scores + bf16 copy (single read of features) ----
    int gid  = (blockIdx.x - NBLK2) * blockDim.x + threadIdx.x;
    int node = gid >> 4;
    int lane = gid & 15;
    if (node >= n_nodes) return;
    const float4 f  = *reinterpret_cast<const float4*>(feat + (size_t)node * DIM + lane * 4);
    const float4 as = *reinterpret_cast<const float4*>(attn_w + lane * 4);
    const float4 ad = *reinterpret_cast<const float4*>(attn_w + DIM + lane * 4);
    float ps = f.x * as.x + f.y * as.y + f.z * as.z + f.w * as.w;
    float pd = f.x * ad.x + f.y * ad.y + f.z * ad.z + f.w * ad.w;
    uint b0 = __float_as_uint(f.x), b1 = __float_as_uint(f.y);
    uint b2 = __float_as_uint(f.z), b3 = __float_as_uint(f.w);
    ushort4 h;
    h.x = (unsigned short)((b0 + 0x7FFFu + ((b0 >> 16) & 1u)) >> 16);
    h.y = (unsigned short)((b1 + 0x7FFFu + ((b1 >> 16) & 1u)) >> 16);
    h.z = (unsigned short)((b2 + 0x7FFFu + ((b2 >> 16) & 1u)) >> 16);
    h.w = (unsigned short)((b3 + 0x7FFFu + ((b3 >> 16) & 1u)) >> 16);
    *reinterpret_cast<ushort4*>(fbf + (size_t)node * DIM + lane * 4) = h;
    for (int off = 8; off >= 1; off >>= 1) {
        ps += __shfl_xor(ps, off, 16);
        pd += __shfl_xor(pd, off, 16);
    }
    if (lane == 0) {
        s_src[node] = ps;
        s_dst[node] = pd;
    }
}

// ---------------------------------------------------------------------------
// Scan level 1 over bin-major logical order, reading the block-major
// histogram with a strided index (1 MB, L2-resident -> transpose kernel
// is unnecessary). Writes PARTIAL exclusive scan (bin-major) + block sums.
// Consumers add bsum[g >> 10] to get absolute offsets.
// ---------------------------------------------------------------------------
__global__ void scan1_strided(const int* __restrict__ bcntT,
                              int* __restrict__ out,
                              int* __restrict__ bsum) {
    __shared__ int tmp[SCAN_BLOCK];
    int t = threadIdx.x;
    int g = blockIdx.x * SCAN_BLOCK + t;          // g = bin*NBLK2 + blk
    int v = bcntT[(size_t)(g & (NBLK2 - 1)) * NB1 + (g >> 8)];
    tmp[t] = v;
    __syncthreads();
    for (int off = 1; off < SCAN_BLOCK; off <<= 1) {
        int u = (t >= off) ? tmp[t - off] : 0;
        __syncthreads();
        tmp[t] += u;
        __syncthreads();
    }
    out[g] = tmp[t] - v;                          // exclusive (partial)
    if (t == SCAN_BLOCK - 1) bsum[blockIdx.x] = tmp[t];
}

__global__ void scan_level2(int* __restrict__ bsum, int nb) {
    __shared__ int tmp[SCAN_BLOCK];
    int t = threadIdx.x;
    int v = (t < nb) ? bsum[t] : 0;
    tmp[t] = v;
    __syncthreads();
    for (int off = 1; off < SCAN_BLOCK; off <<= 1) {
        int u = (t >= off) ? tmp[t - off] : 0;
        __syncthreads();
        tmp[t] += u;
        __syncthreads();
    }
    if (t < nb) bsum[t] = tmp[t] - v;             // exclusive
}

// ---------------------------------------------------------------------------
// Scatter edges into coarse buckets; reads the partial scan strided and adds
// the level-2 block offset directly (no back-transpose, no scan_level3).
// ---------------------------------------------------------------------------
__global__ void coarse_scatter2(const int* __restrict__ src,
                                const int* __restrict__ dst,
                                const int* __restrict__ bcnt,
                                const int* __restrict__ bsum,
                                int* __restrict__ bpk, int m) {
    __shared__ int lbase[NB1];
    int blk = blockIdx.x;
    for (int t = threadIdx.x; t < NB1; t += blockDim.x) {
        int g = t * NBLK2 + blk;
        lbase[t] = bcnt[g] + bsum[g >> 10];
    }
    __syncthreads();
    int chunk = (m + NBLK2 - 1) / NBLK2;
    int lo = blk * chunk;
    int hi = min(m, lo + chunk);
    for (int i = lo + threadIdx.x; i < hi; i += blockDim.x) {
        int d = dst[i];
        int p = atomicAdd(&lbase[d >> BUCKET_BITS], 1);      // LDS atomic
        bpk[p] = src[i] | ((d & (BUCKET_SZ - 1)) << SRC_SHIFT);
    }
}

// ---------------------------------------------------------------------------
// One block per 128-node bucket; exact per-dst sort via LDS.
// ---------------------------------------------------------------------------
__global__ void fine_sort2(const int* __restrict__ bpk,
                           const int* __restrict__ bcnt,
                           const int* __restrict__ bsum,
                           int* __restrict__ esrc,
                           int* __restrict__ offs,
                           int* __restrict__ deg,
                           int n) {
    __shared__ int cnt[BUCKET_SZ];
    __shared__ int sA[BUCKET_SZ];
    __shared__ int sB[BUCKET_SZ];
    int b = blockIdx.x, t = threadIdx.x;
    int g0 = b * NBLK2, g1 = (b + 1) * NBLK2;
    int start = bcnt[g0] + bsum[g0 >> 10];
    int end   = bcnt[g1] + bsum[g1 >> 10];
    if (t < BUCKET_SZ) cnt[t] = 0;
    __syncthreads();
    for (int e = start + t; e < end; e += blockDim.x)
        atomicAdd(&cnt[(bpk[e] >> SRC_SHIFT) & (BUCKET_SZ - 1)], 1);
    __syncthreads();
    if (t < BUCKET_SZ) sA[t] = cnt[t];
    __syncthreads();
    int* pin = sA; int* pout = sB;
    for (int off = 1; off < BUCKET_SZ; off <<= 1) {          // Hillis-Steele
        if (t < BUCKET_SZ) pout[t] = (t >= off) ? pin[t] + pin[t - off] : pin[t];
        __syncthreads();
        int* tmpp = pin; pin = pout; pout = tmpp;
    }
    if (t < BUCKET_SZ) {
        int excl = pin[t] - cnt[t];
        int d0 = b * BUCKET_SZ + t;
        if (d0 < n) { offs[d0] = start + excl; deg[d0] = cnt[t]; }
        pout[t] = start + excl;                              // slot cursor
    }
    __syncthreads();
    for (int e = start + t; e < end; e += blockDim.x) {
        int pk = bpk[e];
        int p = atomicAdd(&pout[(pk >> SRC_SHIFT) & (BUCKET_SZ - 1)], 1);
        esrc[p] = pk & ((1 << SRC_SHIFT) - 1);
    }
}

// ---------------------------------------------------------------------------
// Aggregation v2: 8 lanes/node, dwordx4 (16B) feature gathers, weights
// computed ONCE per edge (lane p of the 8-lane group computes edge chunk+p,
// then shfl-broadcast). wsum is replicated in all 8 lanes -> no combine.
// ---------------------------------------------------------------------------
__global__ void aggregate_bf16_v2(const int* __restrict__ esrc,
                                  const int* __restrict__ offs,
                                  const int* __restrict__ deg,
                                  const float* __restrict__ s_src,
                                  const float* __restrict__ s_dst,
                                  const unsigned short* __restrict__ fbf,
                                  float* __restrict__ out,
                                  int n) {
    int gid  = blockIdx.x * blockDim.x + threadIdx.x;
    int node = gid >> 3;
    int l8   = gid & 7;
    if (node >= n) return;
    int start = offs[node];
    int cnt   = deg[node];
    float sdd = s_dst[node];
    const uint4* fv4 = reinterpret_cast<const uint4*>(fbf);
    float acc0 = 0.f, acc1 = 0.f, acc2 = 0.f, acc3 = 0.f;
    float acc4 = 0.f, acc5 = 0.f, acc6 = 0.f, acc7 = 0.f;
    float wsum = 0.f;
    for (int e = 0; e < cnt; e += 8) {
        int idx = e + l8;
        int   sv = 0;
        float wv = 0.f;
        if (idx < cnt) {                          // padded chunk: w=0 is a no-op
            sv = esrc[start + idx];               // 8 consecutive ints, coalesced
            wv = __expf(lrelu(s_src[sv] + sdd));  // one exp per EDGE, not per lane
        }
#pragma unroll
        for (int p = 0; p < 8; ++p) {
            float wc = __shfl(wv, p, 8);
            int   sc = __shfl(sv, p, 8);
            uint4 q = fv4[(size_t)sc * 8 + l8];   // 8 lanes x 16B = 128B row
            wsum += wc;
            acc0 += wc * __uint_as_float(q.x << 16);
            acc1 += wc * __uint_as_float(q.x & 0xffff0000u);
            acc2 += wc * __uint_as_float(q.y << 16);
            acc3 += wc * __uint_as_float(q.y & 0xffff0000u);
            acc4 += wc * __uint_as_float(q.z << 16);
            acc5 += wc * __uint_as_float(q.z & 0xffff0000u);
            acc6 += wc * __uint_as_float(q.w << 16);
            acc7 += wc * __uint_as_float(q.w & 0xffff0000u);
        }
    }
    float inv = (cnt > 0) ? 1.f / wsum : 0.f;
    float4 o1, o2;
    o1.x = elu(acc0 * inv); o1.y = elu(acc1 * inv);
    o1.z = elu(acc2 * inv); o1.w = elu(acc3 * inv);
    o2.x = elu(acc4 * inv); o2.y = elu(acc5 * inv);
    o2.z = elu(acc6 * inv); o2.w = elu(acc7 * inv);
    float4* orow = reinterpret_cast<float4*>(out + (size_t)node * DIM + l8 * 8);
    orow[0] = o1;
    orow[1] = o2;
}

// ---------------------------------------------------------------------------
// Fallback path (global-atomic CSR, fp32 features) if ws is too small.
// ---------------------------------------------------------------------------
__global__ void compute_scores(const float* __restrict__ feat,
                               const float* __restrict__ attn_w,
                               float* __restrict__ s_src,
                               float* __restrict__ s_dst,
                               int n_nodes) {
    int gid  = blockIdx.x * blockDim.x + threadIdx.x;
    int node = gid >> 4;
    int lane = gid & 15;
    if (node >= n_nodes) return;
    const float4 f  = *reinterpret_cast<const float4*>(feat + (size_t)node * DIM + lane * 4);
    const float4 as = *reinterpret_cast<const float4*>(attn_w + lane * 4);
    const float4 ad = *reinterpret_cast<const float4*>(attn_w + DIM + lane * 4);
    float ps = f.x * as.x + f.y * as.y + f.z * as.z + f.w * as.w;
    float pd = f.x * ad.x + f.y * ad.y + f.z * ad.z + f.w * ad.w;
    for (int off = 8; off >= 1; off >>= 1) {
        ps += __shfl_xor(ps, off, 16);
        pd += __shfl_xor(pd, off, 16);
    }
    if (lane == 0) { s_src[node] = ps; s_dst[node] = pd; }
}

__global__ void scan_level1(const int* __restrict__ in, int* __restrict__ out,
                            int* __restrict__ bsum, int n) {
    __shared__ int tmp[SCAN_BLOCK];
    int t = threadIdx.x;
    int g = blockIdx.x * SCAN_BLOCK + t;
    int v = (g < n) ? in[g] : 0;
    tmp[t] = v;
    __syncthreads();
    for (int off = 1; off < SCAN_BLOCK; off <<= 1) {
        int u = (t >= off) ? tmp[t - off] : 0;
        __syncthreads();
        tmp[t] += u;
        __syncthreads();
    }
    if (g < n) out[g] = tmp[t] - v;                          // exclusive
    if (t == SCAN_BLOCK - 1) bsum[blockIdx.x] = tmp[t];
}

__global__ void scan_level3(int* __restrict__ out, const int* __restrict__ bsum,
                            int n) {
    int g = blockIdx.x * SCAN_BLOCK + threadIdx.x;
    if (g < n) out[g] += bsum[blockIdx.x];
}

__global__ void degree_rank(const int* __restrict__ dst, int* __restrict__ deg,
                            int* __restrict__ rank, int m) {
    int i = blockIdx.x * blockDim.x + threadIdx.x;
    if (i >= m) return;
    rank[i] = atomicAdd(&deg[dst[i]], 1);
}

__global__ void scatter_src(const int* __restrict__ src, const int* __restrict__ dst,
                            const int* __restrict__ rank, const int* __restrict__ offs,
                            int* __restrict__ esrc, int m) {
    int i = blockIdx.x * blockDim.x + threadIdx.x;
    if (i >= m) return;
    esrc[offs[dst[i]] + rank[i]] = src[i];
}

__global__ void aggregate_f32(const int* __restrict__ esrc,
                              const int* __restrict__ offs,
                              const int* __restrict__ deg,
                              const float* __restrict__ s_src,
                              const float* __restrict__ s_dst,
                              const float* __restrict__ feat,
                              float* __restrict__ out, int n) {
    int gid  = blockIdx.x * blockDim.x + threadIdx.x;
    int node = gid >> 4;
    int lane = gid & 15;
    if (node >= n) return;
    int start = offs[node];
    int cnt   = deg[node];
    float sdd = s_dst[node];
    const float4* fv = reinterpret_cast<const float4*>(feat);
    float4 acc = {0.f, 0.f, 0.f, 0.f};
    float wsum = 0.f;
    for (int e = 0; e < cnt; e++) {
        int s0 = esrc[start + e];
        float w0 = __expf(lrelu(s_src[s0] + sdd));
        float4 f0 = fv[s0 * 16 + lane];
        wsum += w0;
        acc.x += w0 * f0.x; acc.y += w0 * f0.y;
        acc.z += w0 * f0.z; acc.w += w0 * f0.w;
    }
    float inv = (cnt > 0) ? 1.f / wsum : 0.f;
    float4 o;
    o.x = elu(acc.x * inv); o.y = elu(acc.y * inv);
    o.z = elu(acc.z * inv); o.w = elu(acc.w * inv);
    reinterpret_cast<float4*>(out)[node * 16 + lane] = o;
}

extern "C" void kernel_launch(void* const* d_in, const int* in_sizes, int n_in,
                              void* d_out, int out_size, void* d_ws, size_t ws_size,
                              hipStream_t stream) {
    const float* feat   = (const float*)d_in[0];
    const float* attn_w = (const float*)d_in[1];
    const int*   src    = (const int*)d_in[2];
    const int*   dst    = (const int*)d_in[3];

    const int n = in_sizes[0] / DIM;   // n_nodes
    const int m = in_sizes[2];         // n_edges

    float* out = (float*)d_out;

    // ws layout (int-sized slots) — identical to previous version
    float* s_src = (float*)d_ws;                    // n
    float* s_dst = s_src + n;                       // n
    unsigned short* fbf = (unsigned short*)(s_dst + n);  // n*DIM ushorts = n*32 ints
    int*   deg   = (int*)(fbf + (size_t)n * DIM);   // n
    int*   offs  = deg + n;                         // n
    int*   bsum  = offs + n;                        // SCAN_BLOCK
    int*   bcntT = bsum + SCAN_BLOCK;               // LEN2 (block-major counts)
    int*   bcnt  = bcntT + (size_t)LEN2;            // LEN2 (bin-major partial scan)
    int*   bpk   = bcnt + (size_t)LEN2;             // m
    int*   esrc  = bpk + m;                         // m
    size_t need  = ((size_t)(4 + DIM / 2) * n + SCAN_BLOCK + 2 * (size_t)LEN2
                    + 2 * (size_t)m) * sizeof(int);

    if (ws_size >= need) {
        // --- main path: LDS counting sort + bf16 gather, zero global atomics ---
        int PB = (n * 16 + TPB2 - 1) / TPB2;        // prep blocks (1024 thr each)
        prep_and_count<<<NBLK2 + PB, TPB2, 0, stream>>>(
            feat, attn_w, s_src, s_dst, fbf, n, dst, bcntT, m);

        const int nb = LEN2 / SCAN_BLOCK;           // 256
        scan1_strided<<<nb, SCAN_BLOCK, 0, stream>>>(bcntT, bcnt, bsum);
        scan_level2<<<1, SCAN_BLOCK, 0, stream>>>(bsum, nb);

        coarse_scatter2<<<NBLK2, TPB2, 0, stream>>>(src, dst, bcnt, bsum, bpk, m);

        int nbd = (n + BUCKET_SZ - 1) / BUCKET_SZ;  // 782
        fine_sort2<<<nbd, 256, 0, stream>>>(bpk, bcnt, bsum, esrc, offs, deg, n);

        aggregate_bf16_v2<<<(n * 8 + 255) / 256, 256, 0, stream>>>(
            esrc, offs, deg, s_src, s_dst, fbf, out, n);
    } else {
        // --- fallback: global-atomic CSR path, fp32 features ---
        int* deg2  = (int*)(s_dst + n);
        int* offs2 = deg2 + n;
        int* bsum2 = offs2 + n;
        int* rank  = bsum2 + SCAN_BLOCK;
        int* esr2  = rank + m;
        int threads = n * 16;
        compute_scores<<<(threads + 255) / 256, 256, 0, stream>>>(
            feat, attn_w, s_src, s_dst, n);
        hipMemsetAsync(deg2, 0, (size_t)n * sizeof(int), stream);
        degree_rank<<<(m + 255) / 256, 256, 0, stream>>>(dst, deg2, rank, m);
        int nb2 = (n + SCAN_BLOCK - 1) / SCAN_BLOCK;
        scan_level1<<<nb2, SCAN_BLOCK, 0, stream>>>(deg2, offs2, bsum2, n);
        scan_level2<<<1, SCAN_BLOCK, 0, stream>>>(bsum2, nb2);
        scan_level3<<<nb2, SCAN_BLOCK, 0, stream>>>(offs2, bsum2, n);
        scatter_src<<<(m + 255) / 256, 256, 0, stream>>>(src, dst, rank, offs2, esr2, m);
        aggregate_f32<<<(threads + 255) / 256, 256, 0, stream>>>(
            esr2, offs2, deg2, s_src, s_dst, feat, out, n);
    }
}